// Round 1
// baseline (128.569 us; speedup 1.0000x reference)
//
#include <hip/hip_runtime.h>
#include <math.h>

// Problem constants
// B=16, O=24, V=2, P0=32, P1=64, P2=64, R=3, C=16, UI=1, BI=2
// NUM_IN = 32 + 2*64 + 2*1*64 = 288
// P = 24*23 = 552 permutations, lexicographic: p = a*23 + j, second elem bb = j + (j>=a)
// in_tensor layout per (b,p): [nullary(32) | unary[a](64) | unary[bb](64) |
//                              binary[a][j](64) | binary[bb][a-(a>bb)](64)]
// out: [nullary_out (16) | unary_out (16*24) | binary_out (16*24*23)]

#define NBLK_I 72   // 288/4 chunks of 4 inputs

__device__ __forceinline__ float sigmoidf_(float x) {
    return 1.0f / (1.0f + __expf(-x) * 0.0f + expf(-x) * 1.0f - 1.0f + 1.0f) ;
}

// simple exact sigmoid (avoid cleverness)
__device__ __forceinline__ float sigm(float x) { return 1.0f / (1.0f + expf(-x)); }

// ---------------- Kernel 1: softmax prep ----------------
// and_kernel: (3,16,288,3) -> dke layout [r][ichunk=i/4][c][8]: {d0..d3, e0..e3}
__global__ __launch_bounds__(256) void prep_kernel(const float* __restrict__ ak,
                                                   const float* __restrict__ temp,
                                                   float* __restrict__ dke) {
    int idx = blockIdx.x * 256 + threadIdx.x;   // enumerates (r,c,i) = idx over 3*16*288
    if (idx >= 3 * 16 * 288) return;
    int i = idx % 288;
    int c = (idx / 288) % 16;
    int r = idx / (16 * 288);
    float invT = 1.0f / temp[0];
    const float* p = ak + (size_t)idx * 3;
    float a0 = p[0] * invT, a1 = p[1] * invT, a2 = p[2] * invT;
    float mx = fmaxf(a0, fmaxf(a1, a2));
    float e0 = expf(a0 - mx), e1 = expf(a1 - mx), e2 = expf(a2 - mx);
    float inv = 1.0f / (e0 + e1 + e2);
    float s0 = e0 * inv, s1 = e1 * inv, s2 = e2 * inv;
    int ch = i >> 2, lane = i & 3;
    float* q = dke + (((size_t)(r * NBLK_I + ch) * 16 + c) * 8) + lane;
    q[0] = s0 - s1;   // d
    q[4] = s1 + s2;   // e
}

// ---------------- Kernel 2: conjunct products + in-block reductions ----------------
// grid: 16*24 blocks (b, a). block: 128 threads = 16 c * 8 pl; thread owns perms
// j = pl, pl+8, pl+16 (j==23 is padding, masked out).
__global__ __launch_bounds__(128) void conj_kernel(const float* __restrict__ nullary,
                                                   const float* __restrict__ unary,
                                                   const float* __restrict__ binary,
                                                   const float* __restrict__ orK,
                                                   const float* __restrict__ temp,
                                                   const float* __restrict__ dke,
                                                   float* __restrict__ out,
                                                   float* __restrict__ ws0) {
    __shared__ float xs[24 * 296];
    __shared__ float red0[8][16];
    __shared__ float red1[8][16];

    const int tid = threadIdx.x;
    const int blk = blockIdx.x;
    const int b = blk / 24;
    const int a = blk % 24;

    // ---- stage x for 24 perms (23 real + 1 pad) ----
    for (int idx = tid; idx < 24 * NBLK_I; idx += 128) {
        int perm = idx / NBLK_I;
        int chunk = idx % NBLK_I;
        int je = perm < 23 ? perm : 22;           // pad perm stages a copy of j=22
        int bb = je + (je >= a ? 1 : 0);
        int aadj = (a > bb) ? (a - 1) : a;
        const float* src;
        if (chunk < 8)        src = nullary + b * 32 + chunk * 4;
        else if (chunk < 24)  src = unary + ((size_t)b * 24 + a) * 64 + (chunk - 8) * 4;
        else if (chunk < 40)  src = unary + ((size_t)b * 24 + bb) * 64 + (chunk - 24) * 4;
        else if (chunk < 56)  src = binary + (((size_t)b * 24 + a) * 23 + je) * 64 + (chunk - 40) * 4;
        else                  src = binary + (((size_t)b * 24 + bb) * 23 + aadj) * 64 + (chunk - 56) * 4;
        float4 v = *(const float4*)src;
        *(float4*)&xs[perm * 296 + chunk * 4] = v;
    }
    __syncthreads();

    const int c = tid & 15;
    const int pl = tid >> 4;   // 0..7

    float acc[3][3];
#pragma unroll
    for (int m = 0; m < 3; ++m)
#pragma unroll
        for (int r = 0; r < 3; ++r) acc[m][r] = 1.0f;

    const float* kc = dke + c * 8;

    for (int ch = 0; ch < NBLK_I; ++ch) {
        float4 xv[3];
#pragma unroll
        for (int m = 0; m < 3; ++m)
            xv[m] = *(const float4*)&xs[(pl + 8 * m) * 296 + ch * 4];
#pragma unroll
        for (int r = 0; r < 3; ++r) {
            const float* kp = kc + (size_t)(r * NBLK_I + ch) * 128;
            float4 d = *(const float4*)kp;
            float4 e = *(const float4*)(kp + 4);
#pragma unroll
            for (int m = 0; m < 3; ++m) {
                float t0 = fmaf(xv[m].x, d.x, e.x);
                float t1 = fmaf(xv[m].y, d.y, e.y);
                float t2 = fmaf(xv[m].z, d.z, e.z);
                float t3 = fmaf(xv[m].w, d.w, e.w);
                acc[m][r] *= (t0 * t1) * (t2 * t3);
            }
        }
    }

    // ---- reductions ----
    const float T = temp[0];
    const float ok2 = sigm(orK[32 + c] / T);

    // binary: out[b,a,j] = 1 - prod_c(1 - conj2 * ok2[c]); j = pl + 8m
#pragma unroll
    for (int m = 0; m < 3; ++m) {
        int j = pl + 8 * m;
        float w = 1.0f - acc[m][2] * ok2;
#pragma unroll
        for (int off = 1; off < 16; off <<= 1) w *= __shfl_xor(w, off, 16);
        if (c == 0 && j < 23) out[400 + ((size_t)b * 24 + a) * 23 + j] = 1.0f - w;
    }

    // unary + nullary partial products over this block's perms
    float u1 = 1.0f, u0 = 1.0f;
#pragma unroll
    for (int m = 0; m < 3; ++m) {
        int j = pl + 8 * m;
        if (j < 23) {
            u1 *= (1.0f - acc[m][1]);
            u0 *= (1.0f - acc[m][0]);
        }
    }
    red1[pl][c] = u1;
    red0[pl][c] = u0;
    __syncthreads();

    if (tid < 16) {
        int cc = tid;
        float p1 = 1.0f, p0 = 1.0f;
#pragma unroll
        for (int q = 0; q < 8; ++q) { p1 *= red1[q][cc]; p0 *= red0[q][cc]; }
        // unary out: rules = 1 - p1; w = 1 - rules*ok1; probsum over c
        float ok1 = sigm(orK[16 + cc] / T);
        float w = 1.0f - (1.0f - p1) * ok1;
#pragma unroll
        for (int off = 1; off < 16; off <<= 1) w *= __shfl_xor(w, off, 16);
        if (cc == 0) out[16 + (size_t)b * 24 + a] = 1.0f - w;
        // nullary partial: prod over this a-group of (1 - conj0)
        ws0[((size_t)b * 24 + a) * 16 + cc] = p0;
    }
}

// ---------------- Kernel 3: nullary finish ----------------
__global__ __launch_bounds__(256) void final_kernel(const float* __restrict__ ws0,
                                                    const float* __restrict__ orK,
                                                    const float* __restrict__ temp,
                                                    float* __restrict__ out) {
    int tid = threadIdx.x;       // 256 = 16 b * 16 c
    int b = tid >> 4, c = tid & 15;
    float p = 1.0f;
#pragma unroll
    for (int a = 0; a < 24; ++a) p *= ws0[((size_t)b * 24 + a) * 16 + c];
    float T = temp[0];
    float ok0 = sigm(orK[c] / T);
    float w = 1.0f - (1.0f - p) * ok0;
#pragma unroll
    for (int off = 1; off < 16; off <<= 1) w *= __shfl_xor(w, off, 16);
    if (c == 0) out[b] = 1.0f - w;
}

extern "C" void kernel_launch(void* const* d_in, const int* in_sizes, int n_in,
                              void* d_out, int out_size, void* d_ws, size_t ws_size,
                              hipStream_t stream) {
    const float* nullary = (const float*)d_in[0];   // (16,32)
    const float* unary   = (const float*)d_in[1];   // (16,24,64)
    const float* binary  = (const float*)d_in[2];   // (16,24,23,64)
    const float* ak      = (const float*)d_in[3];   // (3,16,288,3)
    const float* orK     = (const float*)d_in[4];   // (3,16)
    const float* temp    = (const float*)d_in[5];   // scalar

    float* out = (float*)d_out;                     // 16 + 384 + 8832 = 9232 floats
    float* dke = (float*)d_ws;                      // 3*72*16*8 = 27648 floats
    float* ws0 = dke + 27648;                       // 16*24*16 = 6144 floats

    prep_kernel<<<54, 256, 0, stream>>>(ak, temp, dke);
    conj_kernel<<<16 * 24, 128, 0, stream>>>(nullary, unary, binary, orK, temp, dke, out, ws0);
    final_kernel<<<1, 256, 0, stream>>>(ws0, orK, temp, out);
}

// Round 3
// 88.310 us; speedup vs baseline: 1.4559x; 1.4559x over previous
//
#include <hip/hip_runtime.h>
#include <math.h>

// Problem constants
// B=16, O=24, V=2, P0=32, P1=64, P2=64, R=3, C=16, UI=1, BI=2
// NUM_IN = 288, P = 552 perms (p = a*23 + j, bb = j + (j>=a))
// in_tensor per (b,p): [nullary(32) | unary[a](64) | unary[bb](64) |
//                       binary[a][j](64) | binary[bb][a-(a>bb)](64)]
// out: [nullary_out(16) | unary_out(16*24) | binary_out(16*24*23)]

#define NBLK_I 72   // 288/4 chunks of 4 inputs

__device__ __forceinline__ float sigm(float x) { return 1.0f / (1.0f + expf(-x)); }

// ---------------- Kernel 1: softmax prep ----------------
// and_kernel: (3,16,288,3) -> dke layout [ch=i/4][c][r][8]: {d0..d3, e0..e3}
// conj term: x*s0 + (1-x)*s1 + s2 = fma(x, s0-s1, s1+s2) = fma(x, d, e)
__global__ __launch_bounds__(256) void prep_kernel(const float* __restrict__ ak,
                                                   const float* __restrict__ temp,
                                                   float* __restrict__ dke) {
    int idx = blockIdx.x * 256 + threadIdx.x;   // (r,c,i) over 3*16*288
    if (idx >= 3 * 16 * 288) return;
    int i = idx % 288;
    int c = (idx / 288) % 16;
    int r = idx / (16 * 288);
    float invT = 1.0f / temp[0];
    const float* p = ak + (size_t)idx * 3;
    float a0 = p[0] * invT, a1 = p[1] * invT, a2 = p[2] * invT;
    float mx = fmaxf(a0, fmaxf(a1, a2));
    float e0 = expf(a0 - mx), e1 = expf(a1 - mx), e2 = expf(a2 - mx);
    float inv = 1.0f / (e0 + e1 + e2);
    float s0 = e0 * inv, s1 = e1 * inv, s2 = e2 * inv;
    int ch = i >> 2, lane = i & 3;
    float* q = dke + (((size_t)(ch * 16 + c) * 3 + r) * 8) + lane;
    q[0] = s0 - s1;   // d
    q[4] = s1 + s2;   // e
}

// ---------------- Kernel 2: conjunct products + in-block reductions ----------------
// grid: 16*24 blocks (b, a). block: 512 threads = iq(4) x pl(8) x c(16).
// thread handles perms j = pl + 8m (m=0..2; j==23 is pad) over chunks [iq*18, iq*18+18).
__global__ __launch_bounds__(512) void conj_kernel(const float* __restrict__ nullary,
                                                   const float* __restrict__ unary,
                                                   const float* __restrict__ binary,
                                                   const float* __restrict__ orK,
                                                   const float* __restrict__ temp,
                                                   const float* __restrict__ dke,
                                                   float* __restrict__ out,
                                                   float* __restrict__ ws0) {
    __shared__ float xs[24 * 296];          // 28.4 KB
    __shared__ float part[4][128][9];       // 18 KB  partial products per iq
    __shared__ float red0[8][16];
    __shared__ float red1[8][16];

    const int tid = threadIdx.x;
    const int blk = blockIdx.x;
    const int b = blk / 24;
    const int a = blk % 24;

    // ---- stage x for 24 perms (23 real + 1 pad) ----
    for (int idx = tid; idx < 24 * NBLK_I; idx += 512) {
        int perm = idx / NBLK_I;
        int chunk = idx % NBLK_I;
        int je = perm < 23 ? perm : 22;     // pad perm = copy of j=22
        int bb = je + (je >= a ? 1 : 0);
        int aadj = (a > bb) ? (a - 1) : a;
        const float* src;
        if (chunk < 8)        src = nullary + b * 32 + chunk * 4;
        else if (chunk < 24)  src = unary + ((size_t)b * 24 + a) * 64 + (chunk - 8) * 4;
        else if (chunk < 40)  src = unary + ((size_t)b * 24 + bb) * 64 + (chunk - 24) * 4;
        else if (chunk < 56)  src = binary + (((size_t)b * 24 + a) * 23 + je) * 64 + (chunk - 40) * 4;
        else                  src = binary + (((size_t)b * 24 + bb) * 23 + aadj) * 64 + (chunk - 56) * 4;
        float4 v = *(const float4*)src;
        *(float4*)&xs[perm * 296 + chunk * 4] = v;
    }
    __syncthreads();

    const int iq = tid >> 7;          // 0..3 : i-segment
    const int pl = (tid >> 4) & 7;    // 0..7
    const int c  = tid & 15;          // 0..15

    float acc[3][3];
#pragma unroll
    for (int m = 0; m < 3; ++m)
#pragma unroll
        for (int r = 0; r < 3; ++r) acc[m][r] = 1.0f;

    const int ch0 = iq * 18;
#pragma unroll 2
    for (int ch = ch0; ch < ch0 + 18; ++ch) {
        float4 xv[3];
#pragma unroll
        for (int m = 0; m < 3; ++m)
            xv[m] = *(const float4*)&xs[(pl + 8 * m) * 296 + ch * 4];
        const float* kp = dke + (size_t)(ch * 16 + c) * 24;
#pragma unroll
        for (int r = 0; r < 3; ++r) {
            float4 d = *(const float4*)(kp + r * 8);
            float4 e = *(const float4*)(kp + r * 8 + 4);
#pragma unroll
            for (int m = 0; m < 3; ++m) {
                float t0 = fmaf(xv[m].x, d.x, e.x);
                float t1 = fmaf(xv[m].y, d.y, e.y);
                float t2 = fmaf(xv[m].z, d.z, e.z);
                float t3 = fmaf(xv[m].w, d.w, e.w);
                acc[m][r] *= (t0 * t1) * (t2 * t3);
            }
        }
    }

    // ---- combine i-segments ----
    {
        float* p = part[iq][pl * 16 + c];
#pragma unroll
        for (int m = 0; m < 3; ++m)
#pragma unroll
            for (int r = 0; r < 3; ++r) p[m * 3 + r] = acc[m][r];
    }
    __syncthreads();

    if (iq == 0) {
        const int row = pl * 16 + c;
#pragma unroll
        for (int m = 0; m < 3; ++m)
#pragma unroll
            for (int r = 0; r < 3; ++r)
                acc[m][r] = part[0][row][m * 3 + r] * part[1][row][m * 3 + r]
                          * part[2][row][m * 3 + r] * part[3][row][m * 3 + r];

        const float T = temp[0];
        const float ok2 = sigm(orK[32 + c] / T);

        // binary: out[b,a,j] = 1 - prod_c(1 - conj2 * ok2[c]); j = pl + 8m
#pragma unroll
        for (int m = 0; m < 3; ++m) {
            int j = pl + 8 * m;
            float w = 1.0f - acc[m][2] * ok2;
#pragma unroll
            for (int off = 1; off < 16; off <<= 1) w *= __shfl_xor(w, off, 16);
            if (c == 0 && j < 23) out[400 + ((size_t)b * 24 + a) * 23 + j] = 1.0f - w;
        }

        // unary + nullary partial products over this block's perms
        float u1 = 1.0f, u0 = 1.0f;
#pragma unroll
        for (int m = 0; m < 3; ++m) {
            int j = pl + 8 * m;
            if (j < 23) {
                u1 *= (1.0f - acc[m][1]);
                u0 *= (1.0f - acc[m][0]);
            }
        }
        red1[pl][c] = u1;
        red0[pl][c] = u0;
    }
    __syncthreads();

    if (tid < 16) {
        int cc = tid;
        float p1 = 1.0f, p0 = 1.0f;
#pragma unroll
        for (int q = 0; q < 8; ++q) { p1 *= red1[q][cc]; p0 *= red0[q][cc]; }
        float T = temp[0];
        float ok1 = sigm(orK[16 + cc] / T);
        float w = 1.0f - (1.0f - p1) * ok1;
#pragma unroll
        for (int off = 1; off < 16; off <<= 1) w *= __shfl_xor(w, off, 16);
        if (cc == 0) out[16 + (size_t)b * 24 + a] = 1.0f - w;
        ws0[((size_t)b * 24 + a) * 16 + cc] = p0;
    }
}

// ---------------- Kernel 3: nullary finish ----------------
__global__ __launch_bounds__(256) void final_kernel(const float* __restrict__ ws0,
                                                    const float* __restrict__ orK,
                                                    const float* __restrict__ temp,
                                                    float* __restrict__ out) {
    int tid = threadIdx.x;       // 256 = 16 b * 16 c
    int b = tid >> 4, c = tid & 15;
    float p = 1.0f;
#pragma unroll
    for (int a = 0; a < 24; ++a) p *= ws0[((size_t)b * 24 + a) * 16 + c];
    float T = temp[0];
    float ok0 = sigm(orK[c] / T);
    float w = 1.0f - (1.0f - p) * ok0;
#pragma unroll
    for (int off = 1; off < 16; off <<= 1) w *= __shfl_xor(w, off, 16);
    if (c == 0) out[b] = 1.0f - w;
}

extern "C" void kernel_launch(void* const* d_in, const int* in_sizes, int n_in,
                              void* d_out, int out_size, void* d_ws, size_t ws_size,
                              hipStream_t stream) {
    const float* nullary = (const float*)d_in[0];   // (16,32)
    const float* unary   = (const float*)d_in[1];   // (16,24,64)
    const float* binary  = (const float*)d_in[2];   // (16,24,23,64)
    const float* ak      = (const float*)d_in[3];   // (3,16,288,3)
    const float* orK     = (const float*)d_in[4];   // (3,16)
    const float* temp    = (const float*)d_in[5];   // scalar

    float* out = (float*)d_out;                     // 16 + 384 + 8832 floats
    float* dke = (float*)d_ws;                      // 72*16*3*8 = 27648 floats
    float* ws0 = dke + 27648;                       // 16*24*16 = 6144 floats

    prep_kernel<<<54, 256, 0, stream>>>(ak, temp, dke);
    conj_kernel<<<16 * 24, 512, 0, stream>>>(nullary, unary, binary, orK, temp, dke, out, ws0);
    final_kernel<<<1, 256, 0, stream>>>(ws0, orK, temp, out);
}

// Round 5
// 88.020 us; speedup vs baseline: 1.4607x; 1.0033x over previous
//
#include <hip/hip_runtime.h>
#include <math.h>

// Problem constants
// B=16, O=24, V=2, P0=32, P1=64, P2=64, R=3, C=16, UI=1, BI=2
// NUM_IN = 288, P = 552 perms (p = a*23 + j, bb = j + (j>=a))
// in_tensor per (b,p): [nullary(32) | unary[a](64) | unary[bb](64) |
//                       binary[a][j](64) | binary[bb][a-(a>bb)](64)]
// out: [nullary_out(16) | unary_out(16*24) | binary_out(16*24*23)]

#define NBLK_I 72   // 288/4 chunks of 4 inputs

__device__ __forceinline__ float sigm(float x) { return 1.0f / (1.0f + expf(-x)); }

// ---------------- Kernel 1: softmax prep ----------------
// and_kernel: (3,16,288,3) -> dke layout [ch=i/4][c][r][8]: {d0..d3, e0..e3}
// conj term: x*s0 + (1-x)*s1 + s2 = fma(x, s0-s1, s1+s2) = fma(x, d, e)
__global__ __launch_bounds__(256) void prep_kernel(const float* __restrict__ ak,
                                                   const float* __restrict__ temp,
                                                   float* __restrict__ dke) {
    int idx = blockIdx.x * 256 + threadIdx.x;   // (r,c,i) over 3*16*288
    if (idx >= 3 * 16 * 288) return;
    int i = idx % 288;
    int c = (idx / 288) % 16;
    int r = idx / (16 * 288);
    float invT = 1.0f / temp[0];
    const float* p = ak + (size_t)idx * 3;
    float a0 = p[0] * invT, a1 = p[1] * invT, a2 = p[2] * invT;
    float mx = fmaxf(a0, fmaxf(a1, a2));
    float e0 = expf(a0 - mx), e1 = expf(a1 - mx), e2 = expf(a2 - mx);
    float inv = 1.0f / (e0 + e1 + e2);
    float s0 = e0 * inv, s1 = e1 * inv, s2 = e2 * inv;
    int ch = i >> 2, lane = i & 3;
    float* q = dke + (((size_t)(ch * 16 + c) * 3 + r) * 8) + lane;
    q[0] = s0 - s1;   // d
    q[4] = s1 + s2;   // e
}

// ---------------- Kernel 2: partial conjunct products ----------------
// grid: 16*24*2 = 768 blocks (b, a, q). block: 512 threads = iq(4) x pl(8) x c(16).
// Block handles chunks [q*36, q*36+36); thread handles 9 chunks (iq segment) for
// perms j = pl + 8m (m=0..2; j==23 pad). In-block iq-combine, then the 128
// combined rows x 9 products go to ws1[block][9][128] (coalesced).
__global__ __launch_bounds__(512) void conj_part(const float* __restrict__ nullary,
                                                 const float* __restrict__ unary,
                                                 const float* __restrict__ binary,
                                                 const float* __restrict__ dke,
                                                 float* __restrict__ ws1) {
    __shared__ float xs[24 * 148];          // 36 chunks * 4 floats, stride 148: 14.2 KB
    __shared__ float part[4][128][9];       // 18.4 KB

    const int tid = threadIdx.x;
    const int blk = blockIdx.x;
    const int b = blk / 48;
    const int rem = blk % 48;
    const int a = rem >> 1;
    const int q = rem & 1;
    const int chbase = q * 36;

    // ---- stage x for 24 perms (23 real + 1 pad), this block's 36 chunks ----
    for (int idx = tid; idx < 24 * 36; idx += 512) {
        int perm = idx / 36;
        int lc = idx % 36;
        int gc = chbase + lc;
        int je = perm < 23 ? perm : 22;     // pad perm = copy of j=22
        int bb = je + (je >= a ? 1 : 0);
        int aadj = (a > bb) ? (a - 1) : a;
        const float* src;
        if (gc < 8)        src = nullary + b * 32 + gc * 4;
        else if (gc < 24)  src = unary + ((size_t)b * 24 + a) * 64 + (gc - 8) * 4;
        else if (gc < 40)  src = unary + ((size_t)b * 24 + bb) * 64 + (gc - 24) * 4;
        else if (gc < 56)  src = binary + (((size_t)b * 24 + a) * 23 + je) * 64 + (gc - 40) * 4;
        else               src = binary + (((size_t)b * 24 + bb) * 23 + aadj) * 64 + (gc - 56) * 4;
        float4 v = *(const float4*)src;
        *(float4*)&xs[perm * 148 + lc * 4] = v;
    }
    __syncthreads();

    const int iq = tid >> 7;          // 0..3 : sub-segment (9 chunks)
    const int pl = (tid >> 4) & 7;    // 0..7
    const int c  = tid & 15;          // 0..15

    float acc[3][3];
#pragma unroll
    for (int m = 0; m < 3; ++m)
#pragma unroll
        for (int r = 0; r < 3; ++r) acc[m][r] = 1.0f;

    const int lc0 = iq * 9;
#pragma unroll 3
    for (int lc = lc0; lc < lc0 + 9; ++lc) {
        float4 xv[3];
#pragma unroll
        for (int m = 0; m < 3; ++m)
            xv[m] = *(const float4*)&xs[(pl + 8 * m) * 148 + lc * 4];
        const float* kp = dke + (size_t)((chbase + lc) * 16 + c) * 24;
#pragma unroll
        for (int r = 0; r < 3; ++r) {
            float4 d = *(const float4*)(kp + r * 8);
            float4 e = *(const float4*)(kp + r * 8 + 4);
#pragma unroll
            for (int m = 0; m < 3; ++m) {
                float t0 = fmaf(xv[m].x, d.x, e.x);
                float t1 = fmaf(xv[m].y, d.y, e.y);
                float t2 = fmaf(xv[m].z, d.z, e.z);
                float t3 = fmaf(xv[m].w, d.w, e.w);
                acc[m][r] *= (t0 * t1) * (t2 * t3);
            }
        }
    }

    // ---- combine iq segments, write 128x9 tile ----
    {
        float* p = part[iq][pl * 16 + c];
#pragma unroll
        for (int m = 0; m < 3; ++m)
#pragma unroll
            for (int r = 0; r < 3; ++r) p[m * 3 + r] = acc[m][r];
    }
    __syncthreads();

    if (iq == 0) {
        const int row = pl * 16 + c;
        float* dst = ws1 + (size_t)blk * 9 * 128;
#pragma unroll
        for (int m = 0; m < 3; ++m)
#pragma unroll
            for (int r = 0; r < 3; ++r)
                dst[(m * 3 + r) * 128 + row] =
                    part[0][row][m * 3 + r] * part[1][row][m * 3 + r]
                  * part[2][row][m * 3 + r] * part[3][row][m * 3 + r];
    }
}

// ---------------- Kernel 3: q-combine + reductions ----------------
// grid: 16*24 blocks (b, a). block: 128 threads = pl(8) x c(16).
__global__ __launch_bounds__(128) void combine_kernel(const float* __restrict__ ws1,
                                                      const float* __restrict__ orK,
                                                      const float* __restrict__ temp,
                                                      float* __restrict__ out,
                                                      float* __restrict__ ws0) {
    __shared__ float red0[8][16];
    __shared__ float red1[8][16];

    const int tid = threadIdx.x;
    const int b = blockIdx.x / 24;
    const int a = blockIdx.x % 24;
    const int pl = tid >> 4;
    const int c = tid & 15;

    const float* s0p = ws1 + ((size_t)(b * 48 + a * 2 + 0) * 9) * 128;
    const float* s1p = ws1 + ((size_t)(b * 48 + a * 2 + 1) * 9) * 128;

    float acc[3][3];
#pragma unroll
    for (int m = 0; m < 3; ++m)
#pragma unroll
        for (int r = 0; r < 3; ++r)
            acc[m][r] = s0p[(m * 3 + r) * 128 + tid] * s1p[(m * 3 + r) * 128 + tid];

    const float T = temp[0];
    const float ok2 = sigm(orK[32 + c] / T);

    // binary: out[b,a,j] = 1 - prod_c(1 - conj2 * ok2[c]); j = pl + 8m
#pragma unroll
    for (int m = 0; m < 3; ++m) {
        int j = pl + 8 * m;
        float w = 1.0f - acc[m][2] * ok2;
#pragma unroll
        for (int off = 1; off < 16; off <<= 1) w *= __shfl_xor(w, off, 16);
        if (c == 0 && j < 23) out[400 + ((size_t)b * 24 + a) * 23 + j] = 1.0f - w;
    }

    // unary + nullary partial products over this block's perms
    float u1 = 1.0f, u0 = 1.0f;
#pragma unroll
    for (int m = 0; m < 3; ++m) {
        int j = pl + 8 * m;
        if (j < 23) {
            u1 *= (1.0f - acc[m][1]);
            u0 *= (1.0f - acc[m][0]);
        }
    }
    red1[pl][c] = u1;
    red0[pl][c] = u0;
    __syncthreads();

    if (tid < 16) {
        int cc = tid;
        float p1 = 1.0f, p0 = 1.0f;
#pragma unroll
        for (int qq = 0; qq < 8; ++qq) { p1 *= red1[qq][cc]; p0 *= red0[qq][cc]; }
        float ok1 = sigm(orK[16 + cc] / T);
        float w = 1.0f - (1.0f - p1) * ok1;
#pragma unroll
        for (int off = 1; off < 16; off <<= 1) w *= __shfl_xor(w, off, 16);
        if (cc == 0) out[16 + (size_t)b * 24 + a] = 1.0f - w;
        ws0[((size_t)b * 24 + a) * 16 + cc] = p0;
    }
}

// ---------------- Kernel 4: nullary finish ----------------
__global__ __launch_bounds__(256) void final_kernel(const float* __restrict__ ws0,
                                                    const float* __restrict__ orK,
                                                    const float* __restrict__ temp,
                                                    float* __restrict__ out) {
    int tid = threadIdx.x;       // 256 = 16 b * 16 c
    int b = tid >> 4, c = tid & 15;
    float p = 1.0f;
#pragma unroll
    for (int a = 0; a < 24; ++a) p *= ws0[((size_t)b * 24 + a) * 16 + c];
    float T = temp[0];
    float ok0 = sigm(orK[c] / T);
    float w = 1.0f - (1.0f - p) * ok0;
#pragma unroll
    for (int off = 1; off < 16; off <<= 1) w *= __shfl_xor(w, off, 16);
    if (c == 0) out[b] = 1.0f - w;
}

extern "C" void kernel_launch(void* const* d_in, const int* in_sizes, int n_in,
                              void* d_out, int out_size, void* d_ws, size_t ws_size,
                              hipStream_t stream) {
    const float* nullary = (const float*)d_in[0];   // (16,32)
    const float* unary   = (const float*)d_in[1];   // (16,24,64)
    const float* binary  = (const float*)d_in[2];   // (16,24,23,64)
    const float* ak      = (const float*)d_in[3];   // (3,16,288,3)
    const float* orK     = (const float*)d_in[4];   // (3,16)
    const float* temp    = (const float*)d_in[5];   // scalar

    float* out = (float*)d_out;                     // 16 + 384 + 8832 floats
    float* dke = (float*)d_ws;                      // 72*16*3*8 = 27648 floats
    float* ws0 = dke + 27648;                       // 16*24*16 = 6144 floats
    float* ws1 = ws0 + 6144;                        // 768*9*128 = 884736 floats

    prep_kernel<<<54, 256, 0, stream>>>(ak, temp, dke);
    conj_part<<<768, 512, 0, stream>>>(nullary, unary, binary, dke, ws1);
    combine_kernel<<<384, 128, 0, stream>>>(ws1, orK, temp, out, ws0);
    final_kernel<<<1, 256, 0, stream>>>(ws0, orK, temp, out);
}

// Round 6
// 85.904 us; speedup vs baseline: 1.4967x; 1.0246x over previous
//
#include <hip/hip_runtime.h>
#include <math.h>

// Problem constants
// B=16, O=24, V=2, P0=32, P1=64, P2=64, R=3, C=16, UI=1, BI=2
// NUM_IN = 288, P = 552 perms (p = a*23 + j, bb = j + (j>=a))
// in_tensor per (b,p): [nullary(32) | unary[a](64) | unary[bb](64) |
//                       binary[a][j](64) | binary[bb][a-(a>bb)](64)]
// out: [nullary_out(16) | unary_out(16*24) | binary_out(16*24*23)]

__device__ __forceinline__ float sigm(float x) { return 1.0f / (1.0f + expf(-x)); }

// ---------------- Kernel 1: softmax prep ----------------
// and_kernel: (3,16,288,3) -> dke layout [ch=i/4][c][r][8]: {d0..d3, e0..e3}
// conj term: x*s0 + (1-x)*s1 + s2 = fma(x, s0-s1, s1+s2) = fma(x, d, e)
__global__ __launch_bounds__(256) void prep_kernel(const float* __restrict__ ak,
                                                   const float* __restrict__ temp,
                                                   float* __restrict__ dke) {
    int idx = blockIdx.x * 256 + threadIdx.x;   // (r,c,i) over 3*16*288
    if (idx >= 3 * 16 * 288) return;
    int i = idx % 288;
    int c = (idx / 288) % 16;
    int r = idx / (16 * 288);
    float invT = 1.0f / temp[0];
    const float* p = ak + (size_t)idx * 3;
    float a0 = p[0] * invT, a1 = p[1] * invT, a2 = p[2] * invT;
    float mx = fmaxf(a0, fmaxf(a1, a2));
    float e0 = expf(a0 - mx), e1 = expf(a1 - mx), e2 = expf(a2 - mx);
    float inv = 1.0f / (e0 + e1 + e2);
    float s0 = e0 * inv, s1 = e1 * inv, s2 = e2 * inv;
    int ch = i >> 2, lane = i & 3;
    float* q = dke + (((size_t)(ch * 16 + c) * 3 + r) * 8) + lane;
    q[0] = s0 - s1;   // d
    q[4] = s1 + s2;   // e
}

// ---------------- Kernel 2: partial conjunct products ----------------
// grid: 16*24*2 = 768 blocks (b, a, q). block: 256 threads = iq(4) x pl(4) x c(16).
// Thread owns 6 perms j = pl + 4m (m=0..5; j==23 is pad) over its 9 chunks
// (iq segment of this block's 36). Each dke load (6 float4 per chunk,c) is
// reused across 6 perms -> dke wave-load count halved vs the 3-perm variant.
__global__ __launch_bounds__(256) void conj_part(const float* __restrict__ nullary,
                                                 const float* __restrict__ unary,
                                                 const float* __restrict__ binary,
                                                 const float* __restrict__ dke,
                                                 float* __restrict__ ws1) {
    __shared__ float xs[24 * 148];          // 14.2 KB (36 chunks * 4 floats, stride 148)
    __shared__ float part[4][64][18];       // 18.4 KB

    const int tid = threadIdx.x;
    const int blk = blockIdx.x;
    const int b = blk / 48;
    const int rem = blk % 48;
    const int a = rem >> 1;
    const int q = rem & 1;
    const int chbase = q * 36;

    // ---- stage x for 24 perms (23 real + 1 pad), this block's 36 chunks ----
    for (int idx = tid; idx < 24 * 36; idx += 256) {
        int perm = idx / 36;
        int lc = idx % 36;
        int gc = chbase + lc;
        int je = perm < 23 ? perm : 22;     // pad perm = copy of j=22
        int bb = je + (je >= a ? 1 : 0);
        int aadj = (a > bb) ? (a - 1) : a;
        const float* src;
        if (gc < 8)        src = nullary + b * 32 + gc * 4;
        else if (gc < 24)  src = unary + ((size_t)b * 24 + a) * 64 + (gc - 8) * 4;
        else if (gc < 40)  src = unary + ((size_t)b * 24 + bb) * 64 + (gc - 24) * 4;
        else if (gc < 56)  src = binary + (((size_t)b * 24 + a) * 23 + je) * 64 + (gc - 40) * 4;
        else               src = binary + (((size_t)b * 24 + bb) * 23 + aadj) * 64 + (gc - 56) * 4;
        float4 v = *(const float4*)src;
        *(float4*)&xs[perm * 148 + lc * 4] = v;
    }
    __syncthreads();

    const int iq = tid >> 6;          // 0..3 : sub-segment (9 chunks)
    const int pl = (tid >> 4) & 3;    // 0..3
    const int c  = tid & 15;          // 0..15

    float acc[6][3];
#pragma unroll
    for (int m = 0; m < 6; ++m)
#pragma unroll
        for (int r = 0; r < 3; ++r) acc[m][r] = 1.0f;

    const int lc0 = iq * 9;
#pragma unroll 3
    for (int lc = lc0; lc < lc0 + 9; ++lc) {
        float4 xv[6];
#pragma unroll
        for (int m = 0; m < 6; ++m)
            xv[m] = *(const float4*)&xs[(pl + 4 * m) * 148 + lc * 4];
        const float* kp = dke + (size_t)((chbase + lc) * 16 + c) * 24;
#pragma unroll
        for (int r = 0; r < 3; ++r) {
            float4 d = *(const float4*)(kp + r * 8);
            float4 e = *(const float4*)(kp + r * 8 + 4);
#pragma unroll
            for (int m = 0; m < 6; ++m) {
                float t0 = fmaf(xv[m].x, d.x, e.x);
                float t1 = fmaf(xv[m].y, d.y, e.y);
                float t2 = fmaf(xv[m].z, d.z, e.z);
                float t3 = fmaf(xv[m].w, d.w, e.w);
                acc[m][r] *= (t0 * t1) * (t2 * t3);
            }
        }
    }

    // ---- combine iq segments, write 64x18 tile ----
    {
        float* p = part[iq][pl * 16 + c];
#pragma unroll
        for (int m = 0; m < 6; ++m)
#pragma unroll
            for (int r = 0; r < 3; ++r) p[m * 3 + r] = acc[m][r];
    }
    __syncthreads();

    if (iq == 0) {
        const int row = pl * 16 + c;
        float* dst = ws1 + (size_t)blk * 18 * 64;
#pragma unroll
        for (int m = 0; m < 6; ++m)
#pragma unroll
            for (int r = 0; r < 3; ++r)
                dst[(m * 3 + r) * 64 + row] =
                    part[0][row][m * 3 + r] * part[1][row][m * 3 + r]
                  * part[2][row][m * 3 + r] * part[3][row][m * 3 + r];
    }
}

// ---------------- Kernel 3: q-combine + reductions (single wave) ----------------
// grid: 16*24 blocks (b, a). block: 64 threads = pl(4) x c(16). Pure shuffles.
__global__ __launch_bounds__(64) void combine_kernel(const float* __restrict__ ws1,
                                                     const float* __restrict__ orK,
                                                     const float* __restrict__ temp,
                                                     float* __restrict__ out,
                                                     float* __restrict__ ws0) {
    const int tid = threadIdx.x;
    const int b = blockIdx.x / 24;
    const int a = blockIdx.x % 24;
    const int pl = tid >> 4;
    const int c = tid & 15;

    const float* s0p = ws1 + ((size_t)(b * 48 + a * 2 + 0) * 18) * 64;
    const float* s1p = ws1 + ((size_t)(b * 48 + a * 2 + 1) * 18) * 64;

    float acc[6][3];
#pragma unroll
    for (int m = 0; m < 6; ++m)
#pragma unroll
        for (int r = 0; r < 3; ++r)
            acc[m][r] = s0p[(m * 3 + r) * 64 + tid] * s1p[(m * 3 + r) * 64 + tid];

    const float T = temp[0];
    const float ok2 = sigm(orK[32 + c] / T);

    // binary: out[b,a,j] = 1 - prod_c(1 - conj2 * ok2[c]); j = pl + 4m
#pragma unroll
    for (int m = 0; m < 6; ++m) {
        int j = pl + 4 * m;
        float w = 1.0f - acc[m][2] * ok2;
#pragma unroll
        for (int off = 1; off < 16; off <<= 1) w *= __shfl_xor(w, off, 16);
        if (c == 0 && j < 23) out[400 + ((size_t)b * 24 + a) * 23 + j] = 1.0f - w;
    }

    // unary + nullary: product over this thread's 6 perms, then across pl via shuffle
    float u1 = 1.0f, u0 = 1.0f;
#pragma unroll
    for (int m = 0; m < 6; ++m) {
        int j = pl + 4 * m;
        if (j < 23) {
            u1 *= (1.0f - acc[m][1]);
            u0 *= (1.0f - acc[m][0]);
        }
    }
    u1 *= __shfl_xor(u1, 16, 64);  u1 *= __shfl_xor(u1, 32, 64);
    u0 *= __shfl_xor(u0, 16, 64);  u0 *= __shfl_xor(u0, 32, 64);

    // unary out
    {
        float ok1 = sigm(orK[16 + c] / T);
        float w = 1.0f - (1.0f - u1) * ok1;
#pragma unroll
        for (int off = 1; off < 16; off <<= 1) w *= __shfl_xor(w, off, 16);
        if (tid == 0) out[16 + (size_t)b * 24 + a] = 1.0f - w;
    }
    // nullary partial
    if (pl == 0) ws0[((size_t)b * 24 + a) * 16 + c] = u0;
}

// ---------------- Kernel 4: nullary finish ----------------
__global__ __launch_bounds__(256) void final_kernel(const float* __restrict__ ws0,
                                                    const float* __restrict__ orK,
                                                    const float* __restrict__ temp,
                                                    float* __restrict__ out) {
    int tid = threadIdx.x;       // 256 = 16 b * 16 c
    int b = tid >> 4, c = tid & 15;
    float p = 1.0f;
#pragma unroll
    for (int a = 0; a < 24; ++a) p *= ws0[((size_t)b * 24 + a) * 16 + c];
    float T = temp[0];
    float ok0 = sigm(orK[c] / T);
    float w = 1.0f - (1.0f - p) * ok0;
#pragma unroll
    for (int off = 1; off < 16; off <<= 1) w *= __shfl_xor(w, off, 16);
    if (c == 0) out[b] = 1.0f - w;
}

extern "C" void kernel_launch(void* const* d_in, const int* in_sizes, int n_in,
                              void* d_out, int out_size, void* d_ws, size_t ws_size,
                              hipStream_t stream) {
    const float* nullary = (const float*)d_in[0];   // (16,32)
    const float* unary   = (const float*)d_in[1];   // (16,24,64)
    const float* binary  = (const float*)d_in[2];   // (16,24,23,64)
    const float* ak      = (const float*)d_in[3];   // (3,16,288,3)
    const float* orK     = (const float*)d_in[4];   // (3,16)
    const float* temp    = (const float*)d_in[5];   // scalar

    float* out = (float*)d_out;                     // 16 + 384 + 8832 floats
    float* dke = (float*)d_ws;                      // 72*16*3*8 = 27648 floats
    float* ws0 = dke + 27648;                       // 16*24*16 = 6144 floats
    float* ws1 = ws0 + 6144;                        // 768*18*64 = 884736 floats

    prep_kernel<<<54, 256, 0, stream>>>(ak, temp, dke);
    conj_part<<<768, 256, 0, stream>>>(nullary, unary, binary, dke, ws1);
    combine_kernel<<<384, 64, 0, stream>>>(ws1, orK, temp, out, ws0);
    final_kernel<<<1, 256, 0, stream>>>(ws0, orK, temp, out);
}

// Round 7
// 85.833 us; speedup vs baseline: 1.4979x; 1.0008x over previous
//
#include <hip/hip_runtime.h>
#include <math.h>

// Problem constants
// B=16, O=24, V=2, P0=32, P1=64, P2=64, R=3, C=16, UI=1, BI=2
// NUM_IN = 288 (72 chunks of 4), P = 552 perms (p = a*23 + j, bb = j + (j>=a))
// in_tensor per (b,p): [nullary(32) | unary[a](64) | unary[bb](64) |
//                       binary[a][j](64) | binary[bb][a-(a>bb)](64)]
// out: [nullary_out(16) | unary_out(16*24) | binary_out(16*24*23)]

#define XST 290   // xs row stride in floats (72*4 = 288, +2 pad)

__device__ __forceinline__ float sigm(float x) { return 1.0f / (1.0f + expf(-x)); }

// ---------------- Kernel 1: softmax prep ----------------
// and_kernel: (3,16,288,3) -> dke layout [ch=i/4][c][r][8]: {d0..d3, e0..e3}
// conj term: x*s0 + (1-x)*s1 + s2 = fma(x, s0-s1, s1+s2) = fma(x, d, e)
__global__ __launch_bounds__(256) void prep_kernel(const float* __restrict__ ak,
                                                   const float* __restrict__ temp,
                                                   float* __restrict__ dke) {
    int idx = blockIdx.x * 256 + threadIdx.x;   // (r,c,i) over 3*16*288
    if (idx >= 3 * 16 * 288) return;
    int i = idx % 288;
    int c = (idx / 288) % 16;
    int r = idx / (16 * 288);
    float invT = 1.0f / temp[0];
    const float* p = ak + (size_t)idx * 3;
    float a0 = p[0] * invT, a1 = p[1] * invT, a2 = p[2] * invT;
    float mx = fmaxf(a0, fmaxf(a1, a2));
    float e0 = expf(a0 - mx), e1 = expf(a1 - mx), e2 = expf(a2 - mx);
    float inv = 1.0f / (e0 + e1 + e2);
    float s0 = e0 * inv, s1 = e1 * inv, s2 = e2 * inv;
    int ch = i >> 2, lane = i & 3;
    float* q = dke + (((size_t)(ch * 16 + c) * 3 + r) * 8) + lane;
    q[0] = s0 - s1;   // d
    q[4] = s1 + s2;   // e
}

// ---------------- Kernel 2: fused conjuncts + combine ----------------
// grid: 16*24 = 384 blocks (b, a). block: 512 threads = iq(8) x pl(4) x c(16).
// Thread: 6 perms j = pl + 4m (m=0..5; j==23 pad) x 9 chunks [iq*9, iq*9+9).
// iq-slices combined through LDS; wave 0 (iq==0) runs the reduction epilogue.
__global__ __launch_bounds__(512, 4) void mega_kernel(const float* __restrict__ nullary,
                                                      const float* __restrict__ unary,
                                                      const float* __restrict__ binary,
                                                      const float* __restrict__ dke,
                                                      const float* __restrict__ orK,
                                                      const float* __restrict__ temp,
                                                      float* __restrict__ out,
                                                      float* __restrict__ ws0) {
    __shared__ float xs[24 * XST];        // 27.8 KB
    __shared__ float part[7][64][18];     // 32.3 KB   (total 60.1 KB -> 2 blocks/CU)

    const int tid = threadIdx.x;
    const int b = blockIdx.x / 24;
    const int a = blockIdx.x % 24;

    // ---- stage x for 24 perms (23 real + 1 pad), all 72 chunks ----
    for (int idx = tid; idx < 24 * 72; idx += 512) {
        int perm = idx / 72;
        int gc = idx % 72;
        int je = perm < 23 ? perm : 22;     // pad perm = copy of j=22
        int bb = je + (je >= a ? 1 : 0);
        int aadj = (a > bb) ? (a - 1) : a;
        const float* src;
        if (gc < 8)        src = nullary + b * 32 + gc * 4;
        else if (gc < 24)  src = unary + ((size_t)b * 24 + a) * 64 + (gc - 8) * 4;
        else if (gc < 40)  src = unary + ((size_t)b * 24 + bb) * 64 + (gc - 24) * 4;
        else if (gc < 56)  src = binary + (((size_t)b * 24 + a) * 23 + je) * 64 + (gc - 40) * 4;
        else               src = binary + (((size_t)b * 24 + bb) * 23 + aadj) * 64 + (gc - 56) * 4;
        float4 v = *(const float4*)src;
        *(float4*)&xs[perm * XST + gc * 4] = v;
    }
    __syncthreads();

    const int iq = tid >> 6;          // 0..7 : 9-chunk segment
    const int pl = (tid >> 4) & 3;    // 0..3
    const int c  = tid & 15;          // 0..15

    float acc[6][3];
#pragma unroll
    for (int m = 0; m < 6; ++m)
#pragma unroll
        for (int r = 0; r < 3; ++r) acc[m][r] = 1.0f;

    const int lc0 = iq * 9;

    // rolling 1-chunk dke register prefetch
    float4 dcur[3], ecur[3];
    {
        const float* kp = dke + (size_t)(lc0 * 16 + c) * 24;
#pragma unroll
        for (int r = 0; r < 3; ++r) {
            dcur[r] = *(const float4*)(kp + r * 8);
            ecur[r] = *(const float4*)(kp + r * 8 + 4);
        }
    }

#pragma unroll 2
    for (int lc = lc0; lc < lc0 + 8; ++lc) {
        float4 dnxt[3], enxt[3];
        {
            const float* kn = dke + (size_t)((lc + 1) * 16 + c) * 24;
#pragma unroll
            for (int r = 0; r < 3; ++r) {
                dnxt[r] = *(const float4*)(kn + r * 8);
                enxt[r] = *(const float4*)(kn + r * 8 + 4);
            }
        }
        float4 xv[6];
#pragma unroll
        for (int m = 0; m < 6; ++m)
            xv[m] = *(const float4*)&xs[(pl + 4 * m) * XST + lc * 4];
#pragma unroll
        for (int r = 0; r < 3; ++r) {
#pragma unroll
            for (int m = 0; m < 6; ++m) {
                float t0 = fmaf(xv[m].x, dcur[r].x, ecur[r].x);
                float t1 = fmaf(xv[m].y, dcur[r].y, ecur[r].y);
                float t2 = fmaf(xv[m].z, dcur[r].z, ecur[r].z);
                float t3 = fmaf(xv[m].w, dcur[r].w, ecur[r].w);
                acc[m][r] *= (t0 * t1) * (t2 * t3);
            }
        }
#pragma unroll
        for (int r = 0; r < 3; ++r) { dcur[r] = dnxt[r]; ecur[r] = enxt[r]; }
    }
    // peeled last chunk
    {
        const int lc = lc0 + 8;
        float4 xv[6];
#pragma unroll
        for (int m = 0; m < 6; ++m)
            xv[m] = *(const float4*)&xs[(pl + 4 * m) * XST + lc * 4];
#pragma unroll
        for (int r = 0; r < 3; ++r) {
#pragma unroll
            for (int m = 0; m < 6; ++m) {
                float t0 = fmaf(xv[m].x, dcur[r].x, ecur[r].x);
                float t1 = fmaf(xv[m].y, dcur[r].y, ecur[r].y);
                float t2 = fmaf(xv[m].z, dcur[r].z, ecur[r].z);
                float t3 = fmaf(xv[m].w, dcur[r].w, ecur[r].w);
                acc[m][r] *= (t0 * t1) * (t2 * t3);
            }
        }
    }

    // ---- combine the 8 iq slices ----
    if (iq >= 1) {
        float* p = part[iq - 1][pl * 16 + c];
#pragma unroll
        for (int m = 0; m < 6; ++m)
#pragma unroll
            for (int r = 0; r < 3; ++r) p[m * 3 + r] = acc[m][r];
    }
    __syncthreads();

    if (iq == 0) {
        const int row = pl * 16 + c;   // == tid (0..63), wave 0
#pragma unroll
        for (int s = 0; s < 7; ++s)
#pragma unroll
            for (int m = 0; m < 6; ++m)
#pragma unroll
                for (int r = 0; r < 3; ++r)
                    acc[m][r] *= part[s][row][m * 3 + r];

        const float T = temp[0];
        const float ok2 = sigm(orK[32 + c] / T);

        // binary: out[b,a,j] = 1 - prod_c(1 - conj2 * ok2[c]); j = pl + 4m
#pragma unroll
        for (int m = 0; m < 6; ++m) {
            int j = pl + 4 * m;
            float w = 1.0f - acc[m][2] * ok2;
#pragma unroll
            for (int off = 1; off < 16; off <<= 1) w *= __shfl_xor(w, off, 16);
            if (c == 0 && j < 23) out[400 + ((size_t)b * 24 + a) * 23 + j] = 1.0f - w;
        }

        // unary + nullary: product over this thread's perms, then across pl
        float u1 = 1.0f, u0 = 1.0f;
#pragma unroll
        for (int m = 0; m < 6; ++m) {
            int j = pl + 4 * m;
            if (j < 23) {
                u1 *= (1.0f - acc[m][1]);
                u0 *= (1.0f - acc[m][0]);
            }
        }
        u1 *= __shfl_xor(u1, 16, 64);  u1 *= __shfl_xor(u1, 32, 64);
        u0 *= __shfl_xor(u0, 16, 64);  u0 *= __shfl_xor(u0, 32, 64);

        // unary out
        {
            float ok1 = sigm(orK[16 + c] / T);
            float w = 1.0f - (1.0f - u1) * ok1;
#pragma unroll
            for (int off = 1; off < 16; off <<= 1) w *= __shfl_xor(w, off, 16);
            if (tid == 0) out[16 + (size_t)b * 24 + a] = 1.0f - w;
        }
        // nullary partial
        if (pl == 0) ws0[((size_t)b * 24 + a) * 16 + c] = u0;
    }
}

// ---------------- Kernel 3: nullary finish ----------------
__global__ __launch_bounds__(256) void final_kernel(const float* __restrict__ ws0,
                                                    const float* __restrict__ orK,
                                                    const float* __restrict__ temp,
                                                    float* __restrict__ out) {
    int tid = threadIdx.x;       // 256 = 16 b * 16 c
    int b = tid >> 4, c = tid & 15;
    float p = 1.0f;
#pragma unroll
    for (int a = 0; a < 24; ++a) p *= ws0[((size_t)b * 24 + a) * 16 + c];
    float T = temp[0];
    float ok0 = sigm(orK[c] / T);
    float w = 1.0f - (1.0f - p) * ok0;
#pragma unroll
    for (int off = 1; off < 16; off <<= 1) w *= __shfl_xor(w, off, 16);
    if (c == 0) out[b] = 1.0f - w;
}

extern "C" void kernel_launch(void* const* d_in, const int* in_sizes, int n_in,
                              void* d_out, int out_size, void* d_ws, size_t ws_size,
                              hipStream_t stream) {
    const float* nullary = (const float*)d_in[0];   // (16,32)
    const float* unary   = (const float*)d_in[1];   // (16,24,64)
    const float* binary  = (const float*)d_in[2];   // (16,24,23,64)
    const float* ak      = (const float*)d_in[3];   // (3,16,288,3)
    const float* orK     = (const float*)d_in[4];   // (3,16)
    const float* temp    = (const float*)d_in[5];   // scalar

    float* out = (float*)d_out;                     // 16 + 384 + 8832 floats
    float* dke = (float*)d_ws;                      // 72*16*3*8 = 27648 floats
    float* ws0 = dke + 27648;                       // 16*24*16 = 6144 floats

    prep_kernel<<<54, 256, 0, stream>>>(ak, temp, dke);
    mega_kernel<<<16 * 24, 512, 0, stream>>>(nullary, unary, binary, dke, orK, temp, out, ws0);
    final_kernel<<<1, 256, 0, stream>>>(ws0, orK, temp, out);
}